// Round 1
// baseline (316.997 us; speedup 1.0000x reference)
//
#include <hip/hip_runtime.h>
#include <hip/hip_bf16.h>

#define BB 4
#define NN 4096
#define MM 4096
#define CC 256
#define ROWS 16
#define CAP 1024

__device__ __forceinline__ float bf2f(unsigned short u) {
    return __uint_as_float(((unsigned)u) << 16);
}
__device__ __forceinline__ unsigned short f2bf(float f) {
    unsigned u = __float_as_uint(f);
    u += 0x7fffu + ((u >> 16) & 1u);   // round-to-nearest-even
    return (unsigned short)(u >> 16);
}

__device__ __forceinline__ float ldval(const float* p) { return *p; }
__device__ __forceinline__ float ldval(const unsigned short* p) { return bf2f(*p); }
__device__ __forceinline__ void stval(float* p, float v) { *p = v; }
__device__ __forceinline__ void stval(unsigned short* p, float v) { *p = f2bf(v); }

// -------- transpose all four weight matrices: Wt[w][c][j] = W[w][j][c] --------
__global__ void transpose4_kernel(const float* __restrict__ Wq, const float* __restrict__ Wk,
                                  const float* __restrict__ Wv, const float* __restrict__ Wm,
                                  float* __restrict__ Wt) {
    int w = blockIdx.y;
    const float* S = (w == 0) ? Wq : (w == 1) ? Wk : (w == 2) ? Wv : Wm;
    int c = blockIdx.x, j = threadIdx.x;
    Wt[(size_t)w * 65536 + (size_t)c * CC + j] = S[(size_t)j * CC + c];
}

// -------- K,V projection (shared A tile), bf16 out, per-batch V column sums --------
__global__ __launch_bounds__(256) void proj_kv_kernel(
    const float* __restrict__ A,            // [B*M, C] nodes_R
    const float* __restrict__ WtK, const float* __restrict__ WtV,
    const float* __restrict__ bK, const float* __restrict__ bV,
    unsigned short* __restrict__ K, unsigned short* __restrict__ V,
    float* __restrict__ Vsum)               // [B, C] zero-initialized
{
    __shared__ float As[ROWS][CC];
    int tid = threadIdx.x;
    size_t r0 = (size_t)blockIdx.x * ROWS;
    for (int r = 0; r < ROWS; r++) As[r][tid] = A[(r0 + r) * CC + tid];
    __syncthreads();
    float accK[ROWS], accV[ROWS];
#pragma unroll
    for (int r = 0; r < ROWS; r++) { accK[r] = 0.f; accV[r] = 0.f; }
    const float* wk = WtK + tid;
    const float* wv = WtV + tid;
    for (int c = 0; c < CC; c += 4) {
        float k0 = wk[(size_t)(c + 0) * CC], k1 = wk[(size_t)(c + 1) * CC];
        float k2 = wk[(size_t)(c + 2) * CC], k3 = wk[(size_t)(c + 3) * CC];
        float v0 = wv[(size_t)(c + 0) * CC], v1 = wv[(size_t)(c + 1) * CC];
        float v2 = wv[(size_t)(c + 2) * CC], v3 = wv[(size_t)(c + 3) * CC];
#pragma unroll
        for (int r = 0; r < ROWS; r++) {
            float4 a = *(const float4*)&As[r][c];
            accK[r] += a.x * k0 + a.y * k1 + a.z * k2 + a.w * k3;
            accV[r] += a.x * v0 + a.y * v1 + a.z * v2 + a.w * v3;
        }
    }
    float bk = bK[tid], bv = bV[tid];
    float vs = 0.f;
    for (int r = 0; r < ROWS; r++) {
        float kk = accK[r] + bk;
        float vv = accV[r] + bv;
        K[(r0 + r) * CC + tid] = f2bf(kk);
        V[(r0 + r) * CC + tid] = f2bf(vv);
        vs += vv;
    }
    int b = (int)(r0 / MM);   // ROWS divides MM, blocks never straddle batches
    atomicAdd(&Vsum[(size_t)b * CC + tid], vs);
}

// -------- single projection: O = A @ Wt + b --------
template <typename AT, typename OT>
__global__ __launch_bounds__(256) void proj_one_kernel(
    const AT* __restrict__ A, const float* __restrict__ Wt,
    const float* __restrict__ bias, OT* __restrict__ O)
{
    __shared__ float As[ROWS][CC];
    int tid = threadIdx.x;
    size_t r0 = (size_t)blockIdx.x * ROWS;
    for (int r = 0; r < ROWS; r++) As[r][tid] = ldval(&A[(r0 + r) * CC + tid]);
    __syncthreads();
    float acc[ROWS];
#pragma unroll
    for (int r = 0; r < ROWS; r++) acc[r] = 0.f;
    const float* w = Wt + tid;
    for (int c = 0; c < CC; c += 4) {
        float w0 = w[(size_t)(c + 0) * CC], w1 = w[(size_t)(c + 1) * CC];
        float w2 = w[(size_t)(c + 2) * CC], w3 = w[(size_t)(c + 3) * CC];
#pragma unroll
        for (int r = 0; r < ROWS; r++) {
            float4 a = *(const float4*)&As[r][c];
            acc[r] += a.x * w0 + a.y * w1 + a.z * w2 + a.w * w3;
        }
    }
    float bb = bias[tid];
    for (int r = 0; r < ROWS; r++) stval(&O[(r0 + r) * CC + tid], acc[r] + bb);
}

// -------- mean of u_R per batch (sum; divided later) --------
__global__ __launch_bounds__(256) void urmean_kernel(const float* __restrict__ kptsR,
                                                     float* __restrict__ Usum) {
    int b = blockIdx.x;
    int tid = threadIdx.x;
    float s = 0.f;
    for (int m = tid; m < MM; m += 256) s += kptsR[((size_t)b * MM + m) * 2 + 0];
#pragma unroll
    for (int off = 32; off; off >>= 1) s += __shfl_xor(s, off);
    __shared__ float sr[4];
    int wave = tid >> 6, lane = tid & 63;
    if (lane == 0) sr[wave] = s;
    __syncthreads();
    if (tid == 0) Usum[b] = sr[0] + sr[1] + sr[2] + sr[3];
}

// -------- sparse epipolar attention, one block per query row --------
__global__ __launch_bounds__(256) void attn_kernel(
    const unsigned short* __restrict__ Q, const unsigned short* __restrict__ K,
    const unsigned short* __restrict__ V,
    const float* __restrict__ kptsL, const float* __restrict__ kptsR,
    const float* __restrict__ Vsum, const float* __restrict__ Usum,
    unsigned short* __restrict__ MT, float* __restrict__ out1, float* __restrict__ out2)
{
    __shared__ float Qs[CC];
    __shared__ unsigned short s_m[CAP];
    __shared__ float s_du[CAP];
    __shared__ float s_p[CAP];
    __shared__ int s_scan[256];
    __shared__ float s_red[8];

    int tid = threadIdx.x;
    int bn = blockIdx.x;
    int b = bn >> 12;                      // N = 4096

    float2 kl = *(const float2*)(kptsL + (size_t)bn * 2);
    float uL = kl.x, vL = kl.y;
    Qs[tid] = bf2f(Q[(size_t)bn * CC + tid]);

    const float2* kR = (const float2*)(kptsR + (size_t)b * MM * 2);
    int m0 = tid * 16;
    int cnt = 0;
#pragma unroll
    for (int i = 0; i < 16; i++) {
        float2 kr = kR[m0 + i];
        float du = uL - kr.x;
        float dv = fabsf(vL - kr.y);
        if (dv < 3.0f && du > 0.0f && du < 192.0f) cnt++;
    }
    s_scan[tid] = cnt;
    __syncthreads();
    for (int off = 1; off < 256; off <<= 1) {
        int add = (tid >= off) ? s_scan[tid - off] : 0;
        __syncthreads();
        s_scan[tid] += add;
        __syncthreads();
    }
    int total = s_scan[255];
    int woff = s_scan[tid] - cnt;
    if (cnt) {
        int o = woff;
#pragma unroll
        for (int i = 0; i < 16; i++) {
            float2 kr = kR[m0 + i];
            float du = uL - kr.x;
            float dv = fabsf(vL - kr.y);
            if (dv < 3.0f && du > 0.0f && du < 192.0f) {
                if (o < CAP) { s_m[o] = (unsigned short)(m0 + i); s_du[o] = du; }
                o++;
            }
        }
    }
    __syncthreads();
    if (total > CAP) total = CAP;          // never expected with this data

    if (total == 0) {
        // all-masked row: softmax over 4096 equal logits -> uniform 1/M
        float mval = Vsum[(size_t)b * CC + tid] * (1.0f / MM);
        MT[(size_t)bn * CC + tid] = f2bf(mval);
        if (tid == 0) {
            out1[bn] = uL - Usum[b] * (1.0f / MM);
            out2[bn] = 0.0f;
        }
        return;
    }

    int wave = tid >> 6, lane = tid & 63;
    // logits: one candidate per wave, lanes split the 256-dim dot product
    const float4* Qs4 = (const float4*)Qs;
    float4 q = Qs4[lane];
    for (int i = wave; i < total; i += 4) {
        const unsigned short* Krow = K + ((size_t)b * MM + s_m[i]) * CC;
        ushort4 kv = *(const ushort4*)(Krow + lane * 4);
        float d = q.x * bf2f(kv.x) + q.y * bf2f(kv.y) + q.z * bf2f(kv.z) + q.w * bf2f(kv.w);
#pragma unroll
        for (int off = 32; off; off >>= 1) d += __shfl_xor(d, off);
        if (lane == 0) s_p[i] = d * 0.0625f;   // 1/sqrt(256)
    }
    __syncthreads();

    // softmax over the valid set (masked entries underflow to exactly 0 in ref)
    float mx = -3.0e38f;
    for (int i = tid; i < total; i += 256) mx = fmaxf(mx, s_p[i]);
#pragma unroll
    for (int off = 32; off; off >>= 1) mx = fmaxf(mx, __shfl_xor(mx, off));
    if (lane == 0) s_red[wave] = mx;
    __syncthreads();
    if (tid == 0)
        s_red[4] = fmaxf(fmaxf(s_red[0], s_red[1]), fmaxf(s_red[2], s_red[3]));
    __syncthreads();
    mx = s_red[4];

    float ps = 0.f, ds = 0.f;
    for (int i = tid; i < total; i += 256) {
        float p = expf(s_p[i] - mx);
        s_p[i] = p;
        ps += p;
        ds += p * s_du[i];
    }
#pragma unroll
    for (int off = 32; off; off >>= 1) {
        ps += __shfl_xor(ps, off);
        ds += __shfl_xor(ds, off);
    }
    __syncthreads();                        // protect s_red reuse (mx was read)
    if (lane == 0) { s_red[wave] = ps; s_red[4 + wave] = ds; }
    __syncthreads();
    if (tid == 0) {
        s_red[0] = s_red[0] + s_red[1] + s_red[2] + s_red[3];
        s_red[4] = s_red[4] + s_red[5] + s_red[6] + s_red[7];
    }
    __syncthreads();
    float S = s_red[0];
    float inv = 1.0f / S;

    // matched[c] = sum_i w_i * V[m_i][c]
    float acc = 0.f;
    for (int i = 0; i < total; i++) {
        const unsigned short* Vrow = V + ((size_t)b * MM + s_m[i]) * CC;
        acc += s_p[i] * bf2f(Vrow[tid]);
    }
    MT[(size_t)bn * CC + tid] = f2bf(acc * inv);
    if (tid == 0) {
        out1[bn] = s_red[4] * inv;
        out2[bn] = 1.0f;
    }
}

extern "C" void kernel_launch(void* const* d_in, const int* in_sizes, int n_in,
                              void* d_out, int out_size, void* d_ws, size_t ws_size,
                              hipStream_t stream) {
    const float* nodes_L = (const float*)d_in[0];
    const float* nodes_R = (const float*)d_in[1];
    const float* kpts_L  = (const float*)d_in[2];
    const float* kpts_R  = (const float*)d_in[3];
    const float* Wq = (const float*)d_in[4];
    const float* bq = (const float*)d_in[5];
    const float* Wk = (const float*)d_in[6];
    const float* bk = (const float*)d_in[7];
    const float* Wv = (const float*)d_in[8];
    const float* bv = (const float*)d_in[9];
    const float* Wm = (const float*)d_in[10];
    const float* bm = (const float*)d_in[11];

    float* wt = (float*)d_ws;                                   // 4 * 65536 f32
    unsigned short* Q  = (unsigned short*)(wt + 4 * 65536);     // bf16 [B*N,C]
    unsigned short* K  = Q + (size_t)BB * NN * CC;              // bf16 [B*M,C]
    unsigned short* V  = K + (size_t)BB * MM * CC;              // bf16 [B*M,C]
    unsigned short* MT = V + (size_t)BB * MM * CC;              // bf16 [B*N,C]
    float* Vsum = (float*)(MT + (size_t)BB * NN * CC);          // [B,C]
    float* Usum = Vsum + BB * CC;                               // [B]

    float* out0 = (float*)d_out;
    float* out1 = out0 + (size_t)BB * NN * CC;
    float* out2 = out1 + (size_t)BB * NN;

    hipMemsetAsync(Vsum, 0, (size_t)BB * CC * sizeof(float), stream);

    transpose4_kernel<<<dim3(CC, 4), dim3(CC), 0, stream>>>(Wq, Wk, Wv, Wm, wt);

    proj_kv_kernel<<<dim3(BB * MM / ROWS), dim3(256), 0, stream>>>(
        nodes_R, wt + 1 * 65536, wt + 2 * 65536, bk, bv, K, V, Vsum);

    proj_one_kernel<float, unsigned short><<<dim3(BB * NN / ROWS), dim3(256), 0, stream>>>(
        nodes_L, wt + 0 * 65536, bq, Q);

    urmean_kernel<<<dim3(BB), dim3(256), 0, stream>>>(kpts_R, Usum);

    attn_kernel<<<dim3(BB * NN), dim3(256), 0, stream>>>(
        Q, K, V, kpts_L, kpts_R, Vsum, Usum, MT, out1, out2);

    proj_one_kernel<unsigned short, float><<<dim3(BB * NN / ROWS), dim3(256), 0, stream>>>(
        MT, wt + 3 * 65536, bm, out0);
}